// Round 3
// baseline (913.981 us; speedup 1.0000x reference)
//
#include <hip/hip_runtime.h>
#include <stdint.h>

#define NB 4
#define NC 64
#define NH 192
#define NW 192

typedef __attribute__((ext_vector_type(8))) short bf16x8;
typedef __attribute__((ext_vector_type(4))) float f32x4;
typedef unsigned short u16;
typedef unsigned int u32;

__device__ inline float bf2f(u16 x){ u32 u = ((u32)x) << 16; return __builtin_bit_cast(float, u); }
__device__ inline u16 f2bf(float f){ u32 u = __builtin_bit_cast(u32, f); u32 r = u + 0x7fffu + ((u >> 16) & 1u); return (u16)(r >> 16); }
__device__ inline bf16x8 packf8(float4 a, float4 b){
  bf16x8 r;
  r[0]=(short)f2bf(a.x); r[1]=(short)f2bf(a.y); r[2]=(short)f2bf(a.z); r[3]=(short)f2bf(a.w);
  r[4]=(short)f2bf(b.x); r[5]=(short)f2bf(b.y); r[6]=(short)f2bf(b.z); r[7]=(short)f2bf(b.w);
  return r;
}

// ---------------- weight transform: f32 OIHW [co][ci][ky][kx] -> bf16 [r][co][ci] ----------------
__global__ void wxform_k(const float* __restrict__ w0, const float* __restrict__ w1,
                         const float* __restrict__ w2, const float* __restrict__ w3,
                         const float* __restrict__ w4, u16* __restrict__ out){
  int idx = blockIdx.x * 256 + threadIdx.x;
  if (idx >= 5 * 36864) return;
  int t = idx / 36864, e = idx % 36864;
  int r = e >> 12, rem = e & 4095, co = rem >> 6, ci = rem & 63;
  const float* src = (t == 0) ? w0 : (t == 1) ? w1 : (t == 2) ? w2 : (t == 3) ? w3 : w4;
  out[idx] = f2bf(src[co * 576 + ci * 9 + r]);
}

// ---------------- f32 NCHW -> bf16 NHWC ----------------
__global__ __launch_bounds__(192) void nchw2nhwc_k(const float* __restrict__ in, u16* __restrict__ out){
  int bh = blockIdx.x; int b = bh / NH, h = bh % NH;
  int w = threadIdx.x;
  u16 v[64];
  const float* p = in + ((size_t)b * NC * NH + h) * NW + w;
#pragma unroll
  for (int c = 0; c < 64; ++c) v[c] = f2bf(p[(size_t)c * NH * NW]);
  uint4* q4 = (uint4*)(out + ((size_t)bh * NW + w) * NC);
#pragma unroll
  for (int i = 0; i < 8; ++i){
    uint4 t;
    t.x = (u32)v[i*8+0] | ((u32)v[i*8+1] << 16);
    t.y = (u32)v[i*8+2] | ((u32)v[i*8+3] << 16);
    t.z = (u32)v[i*8+4] | ((u32)v[i*8+5] << 16);
    t.w = (u32)v[i*8+6] | ((u32)v[i*8+7] << 16);
    q4[i] = t;
  }
}

// ---------------- bf16 -> f32 expand (same layout) ----------------
__global__ __launch_bounds__(256) void bf2f_k(const u16* __restrict__ in, float* __restrict__ out){
  int i = blockIdx.x * 256 + threadIdx.x;   // over BUF/8
  uint4 v = ((const uint4*)in)[i];
  float4 f0, f1;
  f0.x = bf2f((u16)(v.x & 0xffff)); f0.y = bf2f((u16)(v.x >> 16));
  f0.z = bf2f((u16)(v.y & 0xffff)); f0.w = bf2f((u16)(v.y >> 16));
  f1.x = bf2f((u16)(v.z & 0xffff)); f1.y = bf2f((u16)(v.z >> 16));
  f1.z = bf2f((u16)(v.w & 0xffff)); f1.w = bf2f((u16)(v.w >> 16));
  ((float4*)out)[2*i]   = f0;
  ((float4*)out)[2*i+1] = f1;
}

// ---------------- conv3x3 v5: 2 rows x 96 w per block, M=64 per wave ----------------
// grid 768 = (2 w-halves) x (384 strips of 2 rows); block 256 = 4 waves.
// wave = (row 0/1) x (w-half-of-96: 48 w), each wave computes 64co x 48w (mt=4, nt=3).
// B-fragment shared across 4 co-tiles -> LDS b128 reads per output row halved vs v2.
// Single-shot: stage 4 halo rows -> 1 barrier -> compute -> store. LDS 56,448 B -> 2 blocks/CU.
__global__ __launch_bounds__(256) void conv3_k(const u16* __restrict__ in, const u16* __restrict__ wt,
    const float* __restrict__ bias, const u16* __restrict__ skip, u16* __restrict__ out, int relu){
  __shared__ __align__(16) u16 xr[4][98 * 72];   // 4 rows (h0-1..h0+2), stride 72 conflict-free
  int blk = blockIdx.x;
  int wh = blk & 1;
  int strip = blk >> 1;
  int g0 = strip * 2;
  int b = g0 / NH, h0 = g0 % NH;        // strips never cross b (192 % 2 == 0)
  int wstart = wh * 96;
  int tid = threadIdx.x;
  int wv = tid >> 6, lane = tid & 63, l15 = lane & 15, qd = lane >> 4;
  int rsel = wv >> 1, whf = wv & 1;

  // stage 4 rows: 98 cols x 8 parts = 784 uint4 per row
#pragma unroll
  for (int slot = 0; slot < 4; ++slot){
    int hh = h0 - 1 + slot;
    bool rowok = (hh >= 0) && (hh < NH);
    const u16* src = in + (((size_t)b * NH + (rowok ? hh : 0)) * NW) * 64;
    for (int k2 = tid; k2 < 784; k2 += 256){
      int x = k2 >> 3, part = k2 & 7;
      int w = wstart - 1 + x;
      uint4 val = make_uint4(0,0,0,0);
      if (rowok && w >= 0 && w < NW) val = *(const uint4*)(src + (size_t)w * 64 + part * 8);
      *(uint4*)&xr[slot][x * 72 + part * 8] = val;
    }
  }
  __syncthreads();

  f32x4 acc[4][3];
#pragma unroll
  for (int mt = 0; mt < 4; ++mt)
#pragma unroll
    for (int nt = 0; nt < 3; ++nt) acc[mt][nt] = (f32x4){0.f,0.f,0.f,0.f};

#pragma unroll
  for (int r = 0; r < 9; ++r){
    int ky = r / 3, kx = r % 3;
    const u16* xbase = xr[rsel + ky];
#pragma unroll
    for (int ks = 0; ks < 2; ++ks){
      int ci = ks * 32 + qd * 8;
      const u16* wp_ = wt + r * 4096 + ci;
      bf16x8 a0 = *(const bf16x8*)(wp_ + (l15) * 64);
      bf16x8 a1 = *(const bf16x8*)(wp_ + (16 + l15) * 64);
      bf16x8 a2 = *(const bf16x8*)(wp_ + (32 + l15) * 64);
      bf16x8 a3 = *(const bf16x8*)(wp_ + (48 + l15) * 64);
#pragma unroll
      for (int nt = 0; nt < 3; ++nt){
        int x = whf * 48 + nt * 16 + l15 + kx;
        bf16x8 bfr = *(const bf16x8*)&xbase[x * 72 + ci];
        acc[0][nt] = __builtin_amdgcn_mfma_f32_16x16x32_bf16(a0, bfr, acc[0][nt], 0, 0, 0);
        acc[1][nt] = __builtin_amdgcn_mfma_f32_16x16x32_bf16(a1, bfr, acc[1][nt], 0, 0, 0);
        acc[2][nt] = __builtin_amdgcn_mfma_f32_16x16x32_bf16(a2, bfr, acc[2][nt], 0, 0, 0);
        acc[3][nt] = __builtin_amdgcn_mfma_f32_16x16x32_bf16(a3, bfr, acc[3][nt], 0, 0, 0);
      }
    }
  }

  int h = h0 + rsel;
  size_t rowbase = ((size_t)(b * NH + h)) * NW * 64;
#pragma unroll
  for (int mt = 0; mt < 4; ++mt){
    int co0 = mt * 16 + qd * 4;
    float4 bb = *(const float4*)(bias + co0);
#pragma unroll
    for (int nt = 0; nt < 3; ++nt){
      int w = wstart + whf * 48 + nt * 16 + l15;
      size_t o = rowbase + (size_t)w * 64 + co0;
      float v0 = acc[mt][nt][0] + bb.x, v1 = acc[mt][nt][1] + bb.y;
      float v2 = acc[mt][nt][2] + bb.z, v3 = acc[mt][nt][3] + bb.w;
      if (relu){ v0 = fmaxf(v0,0.f); v1 = fmaxf(v1,0.f); v2 = fmaxf(v2,0.f); v3 = fmaxf(v3,0.f); }
      if (skip){
        uint2 ss = *(const uint2*)(skip + o);
        v0 += bf2f((u16)(ss.x & 0xffff)); v1 += bf2f((u16)(ss.x >> 16));
        v2 += bf2f((u16)(ss.y & 0xffff)); v3 += bf2f((u16)(ss.y >> 16));
      }
      uint2 st;
      st.x = (u32)f2bf(v0) | ((u32)f2bf(v1) << 16);
      st.y = (u32)f2bf(v2) | ((u32)f2bf(v3) << 16);
      *(uint2*)(out + o) = st;
    }
  }
}

// ---------------- attention v3 (round-1 best: 71.4 us): single P buffer, in-place transpose ----------------
// Q,K: bf16 NHWC rows. X,Y: NCHW (f32 if XYF32 else bf16). Outputs: bf16 NCHW.
// P = softmax_rows(Q K^T); outA^T = Y^T + X^T-rows x P-rows ; outB^T = X^T + Y^T-rows x P^T-rows
template<int XYF32>
__global__ __launch_bounds__(256) void attn_k(const u16* __restrict__ Q, const u16* __restrict__ K,
    const void* __restrict__ Xv, const void* __restrict__ Yv,
    u16* __restrict__ outA, u16* __restrict__ outB){
  __shared__ __align__(16) u16 P[192 * 200];   // 76,800 B -> 2 blocks/CU
  int bh = blockIdx.x, b = bh / NH, h = bh % NH;
  int tid = threadIdx.x, wv = tid >> 6, lane = tid & 63, l15 = lane & 15, qd = lane >> 4;
  size_t rowo = (size_t)bh * NW * 64;
  const u16* Qr = Q + rowo; const u16* Kr = K + rowo;
  const size_t CS = (size_t)NH * NW;              // 36864
  size_t xb0 = (size_t)b * 64 * CS + (size_t)h * NW;
  const float* Xf = (const float*)Xv; const float* Yf = (const float*)Yv;
  const u16* Xb = (const u16*)Xv; const u16* Yb = (const u16*)Yv;

  // ---- phase 1: S = Q K^T, softmax, store P[w][v] (wave-local rows) ----
#pragma unroll 1
  for (int mi = 0; mi < 3; ++mi){
    int mt = wv * 3 + mi;
    f32x4 s[12];
#pragma unroll
    for (int nt = 0; nt < 12; ++nt) s[nt] = (f32x4){0,0,0,0};
#pragma unroll
    for (int ks = 0; ks < 2; ++ks){
      bf16x8 aq = *(const bf16x8*)(Qr + (mt * 16 + l15) * 64 + ks * 32 + qd * 8);
#pragma unroll
      for (int nt = 0; nt < 12; ++nt){
        bf16x8 bk = *(const bf16x8*)(Kr + (nt * 16 + l15) * 64 + ks * 32 + qd * 8);
        s[nt] = __builtin_amdgcn_mfma_f32_16x16x32_bf16(aq, bk, s[nt], 0, 0, 0);
      }
    }
#pragma unroll
    for (int rg = 0; rg < 4; ++rg){
      float mx = -1e30f;
#pragma unroll
      for (int nt = 0; nt < 12; ++nt) mx = fmaxf(mx, s[nt][rg]);
      mx = fmaxf(mx, __shfl_xor(mx, 1));
      mx = fmaxf(mx, __shfl_xor(mx, 2));
      mx = fmaxf(mx, __shfl_xor(mx, 4));
      mx = fmaxf(mx, __shfl_xor(mx, 8));
      float sum = 0.f;
#pragma unroll
      for (int nt = 0; nt < 12; ++nt){ float ev = __expf(s[nt][rg] - mx); s[nt][rg] = ev; sum += ev; }
      sum += __shfl_xor(sum, 1);
      sum += __shfl_xor(sum, 2);
      sum += __shfl_xor(sum, 4);
      sum += __shfl_xor(sum, 8);
      float inv = 1.f / sum;
      int w = mt * 16 + qd * 4 + rg;
#pragma unroll
      for (int nt = 0; nt < 12; ++nt){
        P[w * 200 + nt * 16 + l15] = f2bf(s[nt][rg] * inv);
      }
    }
  }
  // no barrier: phase 2a reads only this wave's own 48 P rows (intra-wave RAW via lgkmcnt)

  // ---- phase 2a: accA^T[c][w] = sum_v X^T[c][v] P[w][v]; outA = accA + Y ----
  {
    f32x4 accA[3][4];
#pragma unroll
    for (int ni = 0; ni < 3; ++ni)
#pragma unroll
      for (int mt = 0; mt < 4; ++mt) accA[ni][mt] = (f32x4){0,0,0,0};
#pragma unroll 1
    for (int ks = 0; ks < 6; ++ks){
      int v0 = ks * 32 + qd * 8;
      bf16x8 aX[4];
#pragma unroll
      for (int mt = 0; mt < 4; ++mt){
        int c = mt * 16 + l15;
        size_t off = xb0 + (size_t)c * CS + v0;
        if (XYF32){
          float4 x0 = *(const float4*)(Xf + off), x1 = *(const float4*)(Xf + off + 4);
          aX[mt] = packf8(x0, x1);
        } else {
          aX[mt] = *(const bf16x8*)(Xb + off);
        }
      }
#pragma unroll
      for (int ni = 0; ni < 3; ++ni){
        int wrow = (wv * 3 + ni) * 16 + l15;
        bf16x8 bP = *(const bf16x8*)&P[wrow * 200 + v0];
#pragma unroll
        for (int mt = 0; mt < 4; ++mt){
          accA[ni][mt] = __builtin_amdgcn_mfma_f32_16x16x32_bf16(aX[mt], bP, accA[ni][mt], 0, 0, 0);
        }
      }
    }
#pragma unroll
    for (int ni = 0; ni < 3; ++ni){
      int w = (wv * 3 + ni) * 16 + l15;
#pragma unroll
      for (int mt = 0; mt < 4; ++mt){
#pragma unroll
        for (int rg = 0; rg < 4; ++rg){
          int c = mt * 16 + qd * 4 + rg;
          size_t o = xb0 + (size_t)c * CS + w;
          float ra = XYF32 ? Yf[o] : bf2f(Yb[o]);
          outA[o] = f2bf(accA[ni][mt][rg] + ra);
        }
      }
    }
  }

  __syncthreads();   // all P writes + phase-2a reads complete before transpose

  // ---- in-place transpose of P[192][192] (16x16 tiles, pair-swap) ----
  {
    int r = tid >> 4, c = tid & 15;
#pragma unroll 1
    for (int TI = 0; TI < 12; ++TI){
      if (c > r){
        u16 a = P[(TI*16 + r)*200 + TI*16 + c];
        u16 d = P[(TI*16 + c)*200 + TI*16 + r];
        P[(TI*16 + r)*200 + TI*16 + c] = d;
        P[(TI*16 + c)*200 + TI*16 + r] = a;
      }
      int TJ = TI + 1;
      for (; TJ + 1 < 12; TJ += 2){
        u16 a0 = P[(TI*16 + r)*200 + TJ*16 + c];
        u16 b0 = P[(TJ*16 + c)*200 + TI*16 + r];
        u16 a1 = P[(TI*16 + r)*200 + (TJ+1)*16 + c];
        u16 b1 = P[((TJ+1)*16 + c)*200 + TI*16 + r];
        P[(TI*16 + r)*200 + TJ*16 + c] = b0;
        P[(TJ*16 + c)*200 + TI*16 + r] = a0;
        P[(TI*16 + r)*200 + (TJ+1)*16 + c] = b1;
        P[((TJ+1)*16 + c)*200 + TI*16 + r] = a1;
      }
      if (TJ < 12){
        u16 a0 = P[(TI*16 + r)*200 + TJ*16 + c];
        u16 b0 = P[(TJ*16 + c)*200 + TI*16 + r];
        P[(TI*16 + r)*200 + TJ*16 + c] = b0;
        P[(TJ*16 + c)*200 + TI*16 + r] = a0;
      }
    }
  }

  __syncthreads();

  // ---- phase 2b: accB^T[c][w] = sum_v Y^T[c][v] Pt[w][v]; outB = accB + X ----
  {
    f32x4 accB[3][4];
#pragma unroll
    for (int ni = 0; ni < 3; ++ni)
#pragma unroll
      for (int mt = 0; mt < 4; ++mt) accB[ni][mt] = (f32x4){0,0,0,0};
#pragma unroll 1
    for (int ks = 0; ks < 6; ++ks){
      int v0 = ks * 32 + qd * 8;
      bf16x8 aY[4];
#pragma unroll
      for (int mt = 0; mt < 4; ++mt){
        int c = mt * 16 + l15;
        size_t off = xb0 + (size_t)c * CS + v0;
        if (XYF32){
          float4 y0 = *(const float4*)(Yf + off), y1 = *(const float4*)(Yf + off + 4);
          aY[mt] = packf8(y0, y1);
        } else {
          aY[mt] = *(const bf16x8*)(Yb + off);
        }
      }
#pragma unroll
      for (int ni = 0; ni < 3; ++ni){
        int wrow = (wv * 3 + ni) * 16 + l15;
        bf16x8 bPt = *(const bf16x8*)&P[wrow * 200 + v0];
#pragma unroll
        for (int mt = 0; mt < 4; ++mt){
          accB[ni][mt] = __builtin_amdgcn_mfma_f32_16x16x32_bf16(aY[mt], bPt, accB[ni][mt], 0, 0, 0);
        }
      }
    }
#pragma unroll
    for (int ni = 0; ni < 3; ++ni){
      int w = (wv * 3 + ni) * 16 + l15;
#pragma unroll
      for (int mt = 0; mt < 4; ++mt){
#pragma unroll
        for (int rg = 0; rg < 4; ++rg){
          int c = mt * 16 + qd * 4 + rg;
          size_t o = xb0 + (size_t)c * CS + w;
          float rb = XYF32 ? Xf[o] : bf2f(Xb[o]);
          outB[o] = f2bf(accB[ni][mt][rg] + rb);
        }
      }
    }
  }
}

extern "C" void kernel_launch(void* const* d_in, const int* in_sizes, int n_in,
                              void* d_out, int out_size, void* d_ws, size_t ws_size,
                              hipStream_t stream){
  const float* low1 = (const float*)d_in[0];
  const float* low2 = (const float*)d_in[1];
  const float* b11 = (const float*)d_in[3];
  const float* b12 = (const float*)d_in[5];
  const float* b21 = (const float*)d_in[7];
  const float* b22 = (const float*)d_in[9];
  const float* bcv = (const float*)d_in[11];
  const size_t BUF = (size_t)NB * NH * NW * NC;   // 9437184 elements
  // ws (bf16): WT | s1 | s2
  u16* WT = (u16*)d_ws;
  u16* s1 = WT + 184320;
  u16* s2 = s1 + BUF;
  // d_out doubles as 4 bf16 scratch slots until the final expand
  u16* o1 = (u16*)d_out;              // L1T (NHWC) -> Q2
  u16* o2 = o1 + BUF;                 // L2T (NHWC) -> K2
  u16* o3 = o1 + 2 * BUF;             // conv temp -> F2 (NCHW)
  u16* o4 = o1 + 3 * BUF;             // conv temp -> F1 (NCHW)
  float* outL = (float*)d_out;
  float* outR = outL + BUF;

  wxform_k<<<dim3(720), dim3(256), 0, stream>>>(
      (const float*)d_in[2], (const float*)d_in[4], (const float*)d_in[6],
      (const float*)d_in[8], (const float*)d_in[10], WT);
  nchw2nhwc_k<<<dim3(NB * NH), dim3(192), 0, stream>>>(low1, o1);   // L1T
  nchw2nhwc_k<<<dim3(NB * NH), dim3(192), 0, stream>>>(low2, o2);   // L2T

#define CONV(in_, wti, bias_, skip_, out_, relu_) \
  conv3_k<<<dim3(768), dim3(256), 0, stream>>>(in_, WT + (wti) * 36864, bias_, skip_, out_, relu_)

  // fe1 @ low1 -> Q1 (s1)
  CONV(o1, 0, b11, (const u16*)nullptr, o3, 1);
  CONV(o3, 1, b12, o1, o4, 0);
  CONV(o4, 4, bcv, (const u16*)nullptr, s1, 0);
  // fe1 @ low2 -> K1 (s2)
  CONV(o2, 0, b11, (const u16*)nullptr, o3, 1);
  CONV(o3, 1, b12, o2, o4, 0);
  CONV(o4, 4, bcv, (const u16*)nullptr, s2, 0);
  // attention 1 (X=low2 f32, Y=low1 f32): F2 = low1 + P1*low2 -> o3 (NCHW), F1 = low2 + P1^T*low1 -> o4
  attn_k<1><<<dim3(NB * NH), dim3(256), 0, stream>>>(s1, s2, (const void*)low2, (const void*)low1, o3, o4);
  // fe2 @ low1 -> Q2 (o1)
  CONV(o1, 2, b21, (const u16*)nullptr, s1, 1);
  CONV(s1, 3, b22, o1, s2, 0);
  CONV(s2, 4, bcv, (const u16*)nullptr, o1, 0);
  // fe2 @ low2 -> K2 (o2)
  CONV(o2, 2, b21, (const u16*)nullptr, s1, 1);
  CONV(s1, 3, b22, o2, s2, 0);
  CONV(s2, 4, bcv, (const u16*)nullptr, o2, 0);
  // attention 2 (X=F1 bf16, Y=F2 bf16): left -> s1 (NCHW bf16), right -> s2
  attn_k<0><<<dim3(NB * NH), dim3(256), 0, stream>>>(o1, o2, (const void*)o4, (const void*)o3, s1, s2);
  // expand bf16 NCHW -> f32 NCHW into d_out
  bf2f_k<<<dim3((int)(BUF / 8 / 256)), dim3(256), 0, stream>>>(s1, outL);
  bf2f_k<<<dim3((int)(BUF / 8 / 256)), dim3(256), 0, stream>>>(s2, outR);
#undef CONV
}

// Round 4
// 604.275 us; speedup vs baseline: 1.5125x; 1.5125x over previous
//
#include <hip/hip_runtime.h>
#include <stdint.h>

#define NB 4
#define NC 64
#define NH 192
#define NW 192

typedef __attribute__((ext_vector_type(8))) short bf16x8;
typedef __attribute__((ext_vector_type(4))) float f32x4;
typedef unsigned short u16;
typedef unsigned int u32;

__device__ inline float bf2f(u16 x){ u32 u = ((u32)x) << 16; return __builtin_bit_cast(float, u); }
__device__ inline u16 f2bf(float f){ u32 u = __builtin_bit_cast(u32, f); u32 r = u + 0x7fffu + ((u >> 16) & 1u); return (u16)(r >> 16); }
__device__ inline bf16x8 packf8(float4 a, float4 b){
  bf16x8 r;
  r[0]=(short)f2bf(a.x); r[1]=(short)f2bf(a.y); r[2]=(short)f2bf(a.z); r[3]=(short)f2bf(a.w);
  r[4]=(short)f2bf(b.x); r[5]=(short)f2bf(b.y); r[6]=(short)f2bf(b.z); r[7]=(short)f2bf(b.w);
  return r;
}

// ---------------- weight transform: f32 OIHW [co][ci][ky][kx] -> bf16 [r][co][ci] ----------------
__global__ void wxform_k(const float* __restrict__ w0, const float* __restrict__ w1,
                         const float* __restrict__ w2, const float* __restrict__ w3,
                         const float* __restrict__ w4, u16* __restrict__ out){
  int idx = blockIdx.x * 256 + threadIdx.x;
  if (idx >= 5 * 36864) return;
  int t = idx / 36864, e = idx % 36864;
  int r = e >> 12, rem = e & 4095, co = rem >> 6, ci = rem & 63;
  const float* src = (t == 0) ? w0 : (t == 1) ? w1 : (t == 2) ? w2 : (t == 3) ? w3 : w4;
  out[idx] = f2bf(src[co * 576 + ci * 9 + r]);
}

// ---------------- f32 NCHW -> bf16 NHWC ----------------
__global__ __launch_bounds__(192) void nchw2nhwc_k(const float* __restrict__ in, u16* __restrict__ out){
  int bh = blockIdx.x; int b = bh / NH, h = bh % NH;
  int w = threadIdx.x;
  u16 v[64];
  const float* p = in + ((size_t)b * NC * NH + h) * NW + w;
#pragma unroll
  for (int c = 0; c < 64; ++c) v[c] = f2bf(p[(size_t)c * NH * NW]);
  uint4* q4 = (uint4*)(out + ((size_t)bh * NW + w) * NC);
#pragma unroll
  for (int i = 0; i < 8; ++i){
    uint4 t;
    t.x = (u32)v[i*8+0] | ((u32)v[i*8+1] << 16);
    t.y = (u32)v[i*8+2] | ((u32)v[i*8+3] << 16);
    t.z = (u32)v[i*8+4] | ((u32)v[i*8+5] << 16);
    t.w = (u32)v[i*8+6] | ((u32)v[i*8+7] << 16);
    q4[i] = t;
  }
}

// ---------------- bf16 -> f32 expand (same layout) ----------------
__global__ __launch_bounds__(256) void bf2f_k(const u16* __restrict__ in, float* __restrict__ out){
  int i = blockIdx.x * 256 + threadIdx.x;   // over BUF/8
  uint4 v = ((const uint4*)in)[i];
  float4 f0, f1;
  f0.x = bf2f((u16)(v.x & 0xffff)); f0.y = bf2f((u16)(v.x >> 16));
  f0.z = bf2f((u16)(v.y & 0xffff)); f0.w = bf2f((u16)(v.y >> 16));
  f1.x = bf2f((u16)(v.z & 0xffff)); f1.y = bf2f((u16)(v.z >> 16));
  f1.z = bf2f((u16)(v.w & 0xffff)); f1.w = bf2f((u16)(v.w >> 16));
  ((float4*)out)[2*i]   = f0;
  ((float4*)out)[2*i+1] = f1;
}

// ---------------- conv3x3 v2 (EXACT round-0 geometry, measured ~35us) + XCD-chunked swizzle ----------------
// grid 512 = (2 w-halves) x (256 strips of 3 rows); block 256 = 4 waves (mh=co-half, wq=w-quarter)
// Swizzle: blk = (blk0%8)*64 + blk0/8 — each XCD owns 32 contiguous strips (~2.4MB input slice,
// fits its 4MB L2), so halo re-reads and same-strip w-half sharing hit local L2.
__global__ __launch_bounds__(256) void conv3_k(const u16* __restrict__ in, const u16* __restrict__ wt,
    const float* __restrict__ bias, const u16* __restrict__ skip, u16* __restrict__ out, int relu){
  __shared__ __align__(16) u16 xr[3][98 * 72];   // stride 72: conflict-free, 42336 B total
  int blk0 = blockIdx.x;
  int blk = (blk0 & 7) * 64 + (blk0 >> 3);   // bijective: 512 = 8 * 64
  int wh = blk & 1;
  int strip = blk >> 1;
  int g0 = strip * 3;
  int b = g0 / NH, h0 = g0 % NH;        // strips never cross b (192 % 3 == 0)
  int wstart = wh * 96;
  int tid = threadIdx.x;
  int wvv = tid >> 6, lane = tid & 63, l15 = lane & 15, qd = lane >> 4;
  int mh = wvv >> 1, wq = wvv & 1;

#define STAGE(hh_) do { \
    int hh = (hh_); \
    int slot = ((hh % 3) + 3) % 3; \
    bool rowok = (hh >= 0) && (hh < NH); \
    const u16* src = in + (((size_t)b * NH + (rowok ? hh : 0)) * NW) * 64; \
    for (int k2 = tid; k2 < 784; k2 += 256){ \
      int x = k2 >> 3, part = k2 & 7; \
      int w = wstart - 1 + x; \
      uint4 val = make_uint4(0,0,0,0); \
      if (rowok && w >= 0 && w < NW) val = *(const uint4*)(src + (size_t)w * 64 + part * 8); \
      *(uint4*)&xr[slot][x * 72 + part * 8] = val; \
    } \
  } while(0)

  STAGE(h0 - 1);
  STAGE(h0);
  for (int j = 0; j < 3; ++j){
    int h = h0 + j;
    STAGE(h + 1);
    __syncthreads();
    f32x4 acc[2][3];
#pragma unroll
    for (int mt = 0; mt < 2; ++mt)
#pragma unroll
      for (int nt = 0; nt < 3; ++nt) acc[mt][nt] = (f32x4){0.f,0.f,0.f,0.f};
#pragma unroll
    for (int r = 0; r < 9; ++r){
      int ky = r / 3, kx = r % 3;
      int hs = h - 1 + ky;
      const u16* xbase = xr[((hs % 3) + 3) % 3];
#pragma unroll
      for (int ks = 0; ks < 2; ++ks){
        int ci = ks * 32 + qd * 8;
        const u16* wp_ = wt + r * 4096 + ci;
        bf16x8 a0 = *(const bf16x8*)(wp_ + (mh * 32 + l15) * 64);
        bf16x8 a1 = *(const bf16x8*)(wp_ + (mh * 32 + 16 + l15) * 64);
#pragma unroll
        for (int nt = 0; nt < 3; ++nt){
          int x = wq * 48 + nt * 16 + l15 + kx;
          bf16x8 bfr = *(const bf16x8*)&xbase[x * 72 + ci];
          acc[0][nt] = __builtin_amdgcn_mfma_f32_16x16x32_bf16(a0, bfr, acc[0][nt], 0, 0, 0);
          acc[1][nt] = __builtin_amdgcn_mfma_f32_16x16x32_bf16(a1, bfr, acc[1][nt], 0, 0, 0);
        }
      }
    }
    size_t rowbase = ((size_t)(b * NH + h)) * NW * 64;
#pragma unroll
    for (int mt = 0; mt < 2; ++mt){
      int co0 = mh * 32 + mt * 16 + qd * 4;
      float4 bb = *(const float4*)(bias + co0);
#pragma unroll
      for (int nt = 0; nt < 3; ++nt){
        int w = wstart + wq * 48 + nt * 16 + l15;
        size_t o = rowbase + (size_t)w * 64 + co0;
        float v0 = acc[mt][nt][0] + bb.x, v1 = acc[mt][nt][1] + bb.y;
        float v2 = acc[mt][nt][2] + bb.z, v3 = acc[mt][nt][3] + bb.w;
        if (relu){ v0 = fmaxf(v0,0.f); v1 = fmaxf(v1,0.f); v2 = fmaxf(v2,0.f); v3 = fmaxf(v3,0.f); }
        if (skip){
          uint2 ss = *(const uint2*)(skip + o);
          v0 += bf2f((u16)(ss.x & 0xffff)); v1 += bf2f((u16)(ss.x >> 16));
          v2 += bf2f((u16)(ss.y & 0xffff)); v3 += bf2f((u16)(ss.y >> 16));
        }
        uint2 st;
        st.x = (u32)f2bf(v0) | ((u32)f2bf(v1) << 16);
        st.y = (u32)f2bf(v2) | ((u32)f2bf(v3) << 16);
        *(uint2*)(out + o) = st;
      }
    }
    __syncthreads();
  }
#undef STAGE
}

// ---------------- attention v3 (round-1 measured 71.3 us): single P buffer, in-place transpose ----------------
// Q,K: bf16 NHWC rows. X,Y: NCHW (f32 if XYF32 else bf16). Outputs: bf16 NCHW.
// P = softmax_rows(Q K^T); outA^T = Y^T + X^T-rows x P-rows ; outB^T = X^T + Y^T-rows x P^T-rows
template<int XYF32>
__global__ __launch_bounds__(256) void attn_k(const u16* __restrict__ Q, const u16* __restrict__ K,
    const void* __restrict__ Xv, const void* __restrict__ Yv,
    u16* __restrict__ outA, u16* __restrict__ outB){
  __shared__ __align__(16) u16 P[192 * 200];   // 76,800 B -> 2 blocks/CU
  int bh = blockIdx.x, b = bh / NH, h = bh % NH;
  int tid = threadIdx.x, wv = tid >> 6, lane = tid & 63, l15 = lane & 15, qd = lane >> 4;
  size_t rowo = (size_t)bh * NW * 64;
  const u16* Qr = Q + rowo; const u16* Kr = K + rowo;
  const size_t CS = (size_t)NH * NW;              // 36864
  size_t xb0 = (size_t)b * 64 * CS + (size_t)h * NW;
  const float* Xf = (const float*)Xv; const float* Yf = (const float*)Yv;
  const u16* Xb = (const u16*)Xv; const u16* Yb = (const u16*)Yv;

  // ---- phase 1: S = Q K^T, softmax, store P[w][v] (wave-local rows) ----
#pragma unroll 1
  for (int mi = 0; mi < 3; ++mi){
    int mt = wv * 3 + mi;
    f32x4 s[12];
#pragma unroll
    for (int nt = 0; nt < 12; ++nt) s[nt] = (f32x4){0,0,0,0};
#pragma unroll
    for (int ks = 0; ks < 2; ++ks){
      bf16x8 aq = *(const bf16x8*)(Qr + (mt * 16 + l15) * 64 + ks * 32 + qd * 8);
#pragma unroll
      for (int nt = 0; nt < 12; ++nt){
        bf16x8 bk = *(const bf16x8*)(Kr + (nt * 16 + l15) * 64 + ks * 32 + qd * 8);
        s[nt] = __builtin_amdgcn_mfma_f32_16x16x32_bf16(aq, bk, s[nt], 0, 0, 0);
      }
    }
#pragma unroll
    for (int rg = 0; rg < 4; ++rg){
      float mx = -1e30f;
#pragma unroll
      for (int nt = 0; nt < 12; ++nt) mx = fmaxf(mx, s[nt][rg]);
      mx = fmaxf(mx, __shfl_xor(mx, 1));
      mx = fmaxf(mx, __shfl_xor(mx, 2));
      mx = fmaxf(mx, __shfl_xor(mx, 4));
      mx = fmaxf(mx, __shfl_xor(mx, 8));
      float sum = 0.f;
#pragma unroll
      for (int nt = 0; nt < 12; ++nt){ float ev = __expf(s[nt][rg] - mx); s[nt][rg] = ev; sum += ev; }
      sum += __shfl_xor(sum, 1);
      sum += __shfl_xor(sum, 2);
      sum += __shfl_xor(sum, 4);
      sum += __shfl_xor(sum, 8);
      float inv = 1.f / sum;
      int w = mt * 16 + qd * 4 + rg;
#pragma unroll
      for (int nt = 0; nt < 12; ++nt){
        P[w * 200 + nt * 16 + l15] = f2bf(s[nt][rg] * inv);
      }
    }
  }
  // no barrier: phase 2a reads only this wave's own 48 P rows (intra-wave RAW via lgkmcnt)

  // ---- phase 2a: accA^T[c][w] = sum_v X^T[c][v] P[w][v]; outA = accA + Y ----
  {
    f32x4 accA[3][4];
#pragma unroll
    for (int ni = 0; ni < 3; ++ni)
#pragma unroll
      for (int mt = 0; mt < 4; ++mt) accA[ni][mt] = (f32x4){0,0,0,0};
#pragma unroll 1
    for (int ks = 0; ks < 6; ++ks){
      int v0 = ks * 32 + qd * 8;
      bf16x8 aX[4];
#pragma unroll
      for (int mt = 0; mt < 4; ++mt){
        int c = mt * 16 + l15;
        size_t off = xb0 + (size_t)c * CS + v0;
        if (XYF32){
          float4 x0 = *(const float4*)(Xf + off), x1 = *(const float4*)(Xf + off + 4);
          aX[mt] = packf8(x0, x1);
        } else {
          aX[mt] = *(const bf16x8*)(Xb + off);
        }
      }
#pragma unroll
      for (int ni = 0; ni < 3; ++ni){
        int wrow = (wv * 3 + ni) * 16 + l15;
        bf16x8 bP = *(const bf16x8*)&P[wrow * 200 + v0];
#pragma unroll
        for (int mt = 0; mt < 4; ++mt){
          accA[ni][mt] = __builtin_amdgcn_mfma_f32_16x16x32_bf16(aX[mt], bP, accA[ni][mt], 0, 0, 0);
        }
      }
    }
#pragma unroll
    for (int ni = 0; ni < 3; ++ni){
      int w = (wv * 3 + ni) * 16 + l15;
#pragma unroll
      for (int mt = 0; mt < 4; ++mt){
#pragma unroll
        for (int rg = 0; rg < 4; ++rg){
          int c = mt * 16 + qd * 4 + rg;
          size_t o = xb0 + (size_t)c * CS + w;
          float ra = XYF32 ? Yf[o] : bf2f(Yb[o]);
          outA[o] = f2bf(accA[ni][mt][rg] + ra);
        }
      }
    }
  }

  __syncthreads();   // all P writes + phase-2a reads complete before transpose

  // ---- in-place transpose of P[192][192] (16x16 tiles, pair-swap) ----
  {
    int r = tid >> 4, c = tid & 15;
#pragma unroll 1
    for (int TI = 0; TI < 12; ++TI){
      if (c > r){
        u16 a = P[(TI*16 + r)*200 + TI*16 + c];
        u16 d = P[(TI*16 + c)*200 + TI*16 + r];
        P[(TI*16 + r)*200 + TI*16 + c] = d;
        P[(TI*16 + c)*200 + TI*16 + r] = a;
      }
      int TJ = TI + 1;
      for (; TJ + 1 < 12; TJ += 2){
        u16 a0 = P[(TI*16 + r)*200 + TJ*16 + c];
        u16 b0 = P[(TJ*16 + c)*200 + TI*16 + r];
        u16 a1 = P[(TI*16 + r)*200 + (TJ+1)*16 + c];
        u16 b1 = P[((TJ+1)*16 + c)*200 + TI*16 + r];
        P[(TI*16 + r)*200 + TJ*16 + c] = b0;
        P[(TJ*16 + c)*200 + TI*16 + r] = a0;
        P[(TI*16 + r)*200 + (TJ+1)*16 + c] = b1;
        P[((TJ+1)*16 + c)*200 + TI*16 + r] = a1;
      }
      if (TJ < 12){
        u16 a0 = P[(TI*16 + r)*200 + TJ*16 + c];
        u16 b0 = P[(TJ*16 + c)*200 + TI*16 + r];
        P[(TI*16 + r)*200 + TJ*16 + c] = b0;
        P[(TJ*16 + c)*200 + TI*16 + r] = a0;
      }
    }
  }

  __syncthreads();

  // ---- phase 2b: accB^T[c][w] = sum_v Y^T[c][v] Pt[w][v]; outB = accB + X ----
  {
    f32x4 accB[3][4];
#pragma unroll
    for (int ni = 0; ni < 3; ++ni)
#pragma unroll
      for (int mt = 0; mt < 4; ++mt) accB[ni][mt] = (f32x4){0,0,0,0};
#pragma unroll 1
    for (int ks = 0; ks < 6; ++ks){
      int v0 = ks * 32 + qd * 8;
      bf16x8 aY[4];
#pragma unroll
      for (int mt = 0; mt < 4; ++mt){
        int c = mt * 16 + l15;
        size_t off = xb0 + (size_t)c * CS + v0;
        if (XYF32){
          float4 y0 = *(const float4*)(Yf + off), y1 = *(const float4*)(Yf + off + 4);
          aY[mt] = packf8(y0, y1);
        } else {
          aY[mt] = *(const bf16x8*)(Yb + off);
        }
      }
#pragma unroll
      for (int ni = 0; ni < 3; ++ni){
        int wrow = (wv * 3 + ni) * 16 + l15;
        bf16x8 bPt = *(const bf16x8*)&P[wrow * 200 + v0];
#pragma unroll
        for (int mt = 0; mt < 4; ++mt){
          accB[ni][mt] = __builtin_amdgcn_mfma_f32_16x16x32_bf16(aY[mt], bPt, accB[ni][mt], 0, 0, 0);
        }
      }
    }
#pragma unroll
    for (int ni = 0; ni < 3; ++ni){
      int w = (wv * 3 + ni) * 16 + l15;
#pragma unroll
      for (int mt = 0; mt < 4; ++mt){
#pragma unroll
        for (int rg = 0; rg < 4; ++rg){
          int c = mt * 16 + qd * 4 + rg;
          size_t o = xb0 + (size_t)c * CS + w;
          float rb = XYF32 ? Xf[o] : bf2f(Xb[o]);
          outB[o] = f2bf(accB[ni][mt][rg] + rb);
        }
      }
    }
  }
}

extern "C" void kernel_launch(void* const* d_in, const int* in_sizes, int n_in,
                              void* d_out, int out_size, void* d_ws, size_t ws_size,
                              hipStream_t stream){
  const float* low1 = (const float*)d_in[0];
  const float* low2 = (const float*)d_in[1];
  const float* b11 = (const float*)d_in[3];
  const float* b12 = (const float*)d_in[5];
  const float* b21 = (const float*)d_in[7];
  const float* b22 = (const float*)d_in[9];
  const float* bcv = (const float*)d_in[11];
  const size_t BUF = (size_t)NB * NH * NW * NC;   // 9437184 elements
  // ws (bf16): WT | s1 | s2
  u16* WT = (u16*)d_ws;
  u16* s1 = WT + 184320;
  u16* s2 = s1 + BUF;
  // d_out doubles as 4 bf16 scratch slots until the final expand
  u16* o1 = (u16*)d_out;              // L1T (NHWC) -> Q2
  u16* o2 = o1 + BUF;                 // L2T (NHWC) -> K2
  u16* o3 = o1 + 2 * BUF;             // conv temp -> F2 (NCHW)
  u16* o4 = o1 + 3 * BUF;             // conv temp -> F1 (NCHW)
  float* outL = (float*)d_out;
  float* outR = outL + BUF;

  wxform_k<<<dim3(720), dim3(256), 0, stream>>>(
      (const float*)d_in[2], (const float*)d_in[4], (const float*)d_in[6],
      (const float*)d_in[8], (const float*)d_in[10], WT);
  nchw2nhwc_k<<<dim3(NB * NH), dim3(192), 0, stream>>>(low1, o1);   // L1T
  nchw2nhwc_k<<<dim3(NB * NH), dim3(192), 0, stream>>>(low2, o2);   // L2T

#define CONV(in_, wti, bias_, skip_, out_, relu_) \
  conv3_k<<<dim3(512), dim3(256), 0, stream>>>(in_, WT + (wti) * 36864, bias_, skip_, out_, relu_)

  // fe1 @ low1 -> Q1 (s1)
  CONV(o1, 0, b11, (const u16*)nullptr, o3, 1);
  CONV(o3, 1, b12, o1, o4, 0);
  CONV(o4, 4, bcv, (const u16*)nullptr, s1, 0);
  // fe1 @ low2 -> K1 (s2)
  CONV(o2, 0, b11, (const u16*)nullptr, o3, 1);
  CONV(o3, 1, b12, o2, o4, 0);
  CONV(o4, 4, bcv, (const u16*)nullptr, s2, 0);
  // attention 1 (X=low2 f32, Y=low1 f32): F2 = low1 + P1*low2 -> o3 (NCHW), F1 = low2 + P1^T*low1 -> o4
  attn_k<1><<<dim3(NB * NH), dim3(256), 0, stream>>>(s1, s2, (const void*)low2, (const void*)low1, o3, o4);
  // fe2 @ low1 -> Q2 (o1)
  CONV(o1, 2, b21, (const u16*)nullptr, s1, 1);
  CONV(s1, 3, b22, o1, s2, 0);
  CONV(s2, 4, bcv, (const u16*)nullptr, o1, 0);
  // fe2 @ low2 -> K2 (o2)
  CONV(o2, 2, b21, (const u16*)nullptr, s1, 1);
  CONV(s1, 3, b22, o2, s2, 0);
  CONV(s2, 4, bcv, (const u16*)nullptr, o2, 0);
  // attention 2 (X=F1 bf16, Y=F2 bf16): left -> s1 (NCHW bf16), right -> s2
  attn_k<0><<<dim3(NB * NH), dim3(256), 0, stream>>>(o1, o2, (const void*)o4, (const void*)o3, s1, s2);
  // expand bf16 NCHW -> f32 NCHW into d_out
  bf2f_k<<<dim3((int)(BUF / 8 / 256)), dim3(256), 0, stream>>>(s1, outL);
  bf2f_k<<<dim3((int)(BUF / 8 / 256)), dim3(256), 0, stream>>>(s2, outR);
#undef CONV
}